// Round 10
// baseline (1912.353 us; speedup 1.0000x reference)
//
#include <hip/hip_runtime.h>

#define TT 2048
#define LL 50
#define DD 300
#define HH 100
#define NCC 7

typedef unsigned short u16;
typedef unsigned int u32;
typedef _Float16 f16x2 __attribute__((ext_vector_type(2)));
typedef _Float16 f16x4 __attribute__((ext_vector_type(4)));
typedef _Float16 f16x8 __attribute__((ext_vector_type(8)));
typedef float f32x4 __attribute__((ext_vector_type(4)));

__device__ __forceinline__ float frcp(float x){ return __builtin_amdgcn_rcpf(x); }
__device__ __forceinline__ float sigm(float x){ return frcp(1.f + __expf(-x)); }
__device__ __forceinline__ float ftanh(float x){ return 1.f - 2.f * frcp(1.f + __expf(2.f * x)); }

__device__ __forceinline__ int ld_acq(int* p){
  return __hip_atomic_load(p, __ATOMIC_ACQUIRE, __HIP_MEMORY_SCOPE_AGENT);
}
__device__ __forceinline__ void st_rel(int* p, int v){
  __hip_atomic_store(p, v, __ATOMIC_RELEASE, __HIP_MEMORY_SCOPE_AGENT);
}

// ---------------- Kernel 0: pack conv weights into MFMA B-fragment order ----------------
__global__ __launch_bounds__(256) void k_prep(const float* __restrict__ Wc3,
    const float* __restrict__ Wc4, const float* __restrict__ Wc5, _Float16* __restrict__ wtp)
{
  const int t = blockIdx.x;
  int kki, ntile, kt;
  if (t < 120){ kki = 0; ntile = t / 30;        kt = t % 30; }
  else if (t < 280){ kki = 1; int r = t - 120; ntile = r / 40; kt = r % 40; }
  else { kki = 2; int r = t - 280;             ntile = r / 50; kt = r % 50; }
  const float* W = (kki == 0) ? Wc3 : ((kki == 1) ? Wc4 : Wc5);
  const int kk = 3 + kki;
  #pragma unroll
  for (int u = 0; u < 2; ++u){
    int e = threadIdx.x * 2 + u;       // 0..511
    int lane = e >> 3, i = e & 7;
    int k = kt * 32 + (lane >> 4) * 8 + i;
    int f = ntile * 16 + (lane & 15);
    int j = k / 320, d = k - j * 320;
    float v = (d < DD) ? W[((size_t)f * kk + j) * DD + d] : 0.f;
    wtp[(size_t)t * 512 + e] = (_Float16)v;
  }
}

// ---------------- Kernel 0b: pack Whh_m / Wih_m into packed-row (unit*4+gate) A-fragments ----
__global__ __launch_bounds__(256) void k_prep2(const float* __restrict__ Whh,
    const float* __restrict__ Wih, _Float16* __restrict__ wpkW, _Float16* __restrict__ wpkI)
{
  const float* W = (blockIdx.x == 0) ? Whh : Wih;
  _Float16* dst  = (blockIdx.x == 0) ? wpkW : wpkI;
  for (int idx = threadIdx.x; idx < 28 * 4 * 64 * 8; idx += 256){
    int i = idx & 7, lane = (idx >> 3) & 63, kt = (idx >> 9) & 3, mt = idx >> 11;
    int rl = lane & 15, gp = lane >> 4;
    int p = mt * 16 + rl;
    int k = kt * 32 + gp * 8 + i;
    int uu = p >> 2, g = p & 3;
    float v = (mt < 25 && g < 3 && k < 100) ? W[(size_t)(uu + 100 * g) * 100 + k] : 0.f;
    dst[idx] = (_Float16)v;
  }
}

// ---------------- Kernel 0c: zero sync flags ----------------
__global__ __launch_bounds__(256) void k_zero(int* __restrict__ flags)
{
  int i = blockIdx.x * 256 + threadIdx.x;
  if (i < 2049) flags[i] = 0;
}

// ---------------- Kernel 1: fused persistent pipeline (320 threads / 5 waves) ----------------
// Block 0: context-GRU scan — BYTE-IDENTICAL structure to the standalone r5
// kernel that measured 1141us (5 waves x 4 m-tiles, 320 thr), consuming gic
// rows via flags. Blocks 1..255: cnn+gi (4-wave MFMA, wave 4 staging-only),
// then batched att2 (4-wave compute, wave 4 barrier-only) gated on the hid
// watermark. cls fused. r9 ran this at 256 thr / 4 waves x 5 tiles and the
// scan degraded 557->780 ns/step — this restores the proven scan shape.
#define WST 328
#define CH 32
__global__ __launch_bounds__(320, 1) void k_mega(
    const int* __restrict__ sents, const float* __restrict__ emb, const _Float16* __restrict__ wtp,
    const float* __restrict__ bc3, const float* __restrict__ bc4, const float* __restrict__ bc5,
    const float* __restrict__ Wt,  const float* __restrict__ bt,
    const float* __restrict__ Wih_c, const float* __restrict__ bih_c,
    const float* __restrict__ Whh_c, const float* __restrict__ bhh_c,
    const _Float16* __restrict__ wpkW, const _Float16* __restrict__ wpkI,
    const float* __restrict__ bih_m, const float* __restrict__ bhh_m,
    const float* __restrict__ Wcls, const float* __restrict__ bcls,
    float* __restrict__ su, float* __restrict__ gic, float* __restrict__ hid,
    int* __restrict__ flags, float* __restrict__ out)
{
  __shared__ __attribute__((aligned(16))) char smem[147456];
  const int tid = threadIdx.x;
  const int b = blockIdx.x;
  const int lane = tid & 63, wvid = tid >> 6;   // 5 waves
  const int rl = lane & 15, gp = lane >> 4;

  if (b > 0){
    // ================= PHASE A: cnn + gi rows =================
    _Float16* w16 = (_Float16*)smem;             // 52*328 f16 = 34112 B
    float* feats  = (float*)(smem + 34112);      // 192 f
    int*   ids    = (int*)(smem + 34880);        // 50 i
    float* su_l   = (float*)(smem + 35088);      // 100 f (16B aligned)

    for (int s = b - 1; s < TT; s += 255){
      if (tid < LL) ids[tid] = sents[s * LL + tid];
      for (int e = tid; e < 52 * WST / 2; e += 320) ((u32*)w16)[e] = 0u;
      __syncthreads();
      for (int e = tid; e < LL * 75; e += 320){
        int l = e / 75, d4 = (e - l * 75) * 4;
        float4 v = *(const float4*)&emb[(size_t)ids[l] * DD + d4];
        _Float16* p = &w16[l * WST + d4];
        p[0] = (_Float16)v.x; p[1] = (_Float16)v.y; p[2] = (_Float16)v.z; p[3] = (_Float16)v.w;
      }
      __syncthreads();

      if (wvid < 4){
        const int kkstart[3] = {0, 120, 280};
        float fmaxv[3];
        #pragma unroll
        for (int kki = 0; kki < 3; ++kki){
          const int nkt = (3 + kki) * 10, Pk = LL - (3 + kki) + 1;
          f32x4 acc0 = {0.f,0.f,0.f,0.f}, acc1 = acc0, acc2 = acc0;
          const f16x8* bp = (const f16x8*)(wtp + (size_t)(kkstart[kki] + wvid * nkt) * 512) + lane;
          int j = 0, d = gp * 8;
          for (int kt = 0; kt < nkt; ++kt){
            f16x8 bb = bp[(size_t)kt * 64];
            f16x8 a0 = *(const f16x8*)&w16[(rl      + j) * WST + d];
            f16x8 a1 = *(const f16x8*)&w16[(16 + rl + j) * WST + d];
            f16x8 a2 = *(const f16x8*)&w16[(32 + rl + j) * WST + d];
            acc0 = __builtin_amdgcn_mfma_f32_16x16x32_f16(a0, bb, acc0, 0, 0, 0);
            acc1 = __builtin_amdgcn_mfma_f32_16x16x32_f16(a1, bb, acc1, 0, 0, 0);
            acc2 = __builtin_amdgcn_mfma_f32_16x16x32_f16(a2, bb, acc2, 0, 0, 0);
            d += 32; if (d >= 320){ d -= 320; ++j; }
          }
          float m = -1e30f;
          #pragma unroll
          for (int r = 0; r < 4; ++r){
            int p0 = gp * 4 + r;
            if (p0 < Pk)      m = fmaxf(m, acc0[r]);
            if (16 + p0 < Pk) m = fmaxf(m, acc1[r]);
            if (32 + p0 < Pk) m = fmaxf(m, acc2[r]);
          }
          m = fmaxf(m, __shfl_xor(m, 16));
          m = fmaxf(m, __shfl_xor(m, 32));
          fmaxv[kki] = m;
        }
        if (lane < 16){
          feats[  0 + wvid * 16 + lane] = fmaxv[0];
          feats[ 64 + wvid * 16 + lane] = fmaxv[1];
          feats[128 + wvid * 16 + lane] = fmaxv[2];
        }
      }
      __syncthreads();
      if (tid < 192){
        float bias = (tid < 64) ? bc3[tid] : ((tid < 128) ? bc4[tid - 64] : bc5[tid - 128]);
        feats[tid] = fmaxf(0.f, feats[tid] + bias);
      }
      __syncthreads();
      if (tid < HH){
        float acc = bt[tid];
        for (int c = 0; c < 192; ++c)
          acc += feats[c] * Wt[c * HH + tid];
        float v = ftanh(acc);
        su[(size_t)s * HH + tid] = v;
        su_l[tid] = v;
      }
      __syncthreads();
      if (s < TT - 1){
        for (int e = tid; e < 300; e += 320){
          const float* wr = Wih_c + (size_t)e * 100;
          float acc = bih_c[e];
          #pragma unroll
          for (int i = 0; i < 25; ++i){
            float4 wv = *(const float4*)(wr + 4 * i);
            float4 xv = *(const float4*)&su_l[4 * i];
            acc += xv.x * wv.x + xv.y * wv.y + xv.z * wv.z + xv.w * wv.w;
          }
          gic[(size_t)s * 300 + e] = acc;
        }
      }
      __syncthreads();                     // drains su/gic stores
      if (tid == 0){ __threadfence(); st_rel(&flags[s], 1); }
    }
  } else {
    // ================= PHASE B: context-GRU scan (r5 structure, 5 waves) =================
    _Float16* h16  = (_Float16*)smem;            // 128 f16
    float* gh_l    = (float*)(smem + 256);       // 304 f
    float* gi_buf  = (float*)(smem + 1472);      // 32*300 f
    float* hid_buf = (float*)(smem + 39872);     // 32*100 f
    const int steps = TT - 1;

    f16x8 afrag[4][4];                           // wave owns m-tiles wvid+5m (r5 layout)
    #pragma unroll
    for (int m = 0; m < 4; ++m){
      int mt = wvid + 5 * m;
      int row = mt * 16 + rl;
      #pragma unroll
      for (int kt = 0; kt < 4; ++kt){
        f16x8 f;
        #pragma unroll
        for (int i = 0; i < 8; ++i){
          int k = kt * 32 + gp * 8 + i;
          float v = (row < 300 && k < 100) ? Whh_c[(size_t)row * 100 + k] : 0.f;
          f[i] = (_Float16)v;
        }
        afrag[m][kt] = f;
      }
    }
    float bhr = 0.f, bhz = 0.f, bhn = 0.f, hreg = 0.f;
    if (tid < HH){ bhr = bhh_c[tid]; bhz = bhh_c[tid + 100]; bhn = bhh_c[tid + 200]; }
    if (tid < 128) h16[tid] = (_Float16)0.f;
    {
      int n0 = steps < CH ? steps : CH;
      for (int e = tid; e < n0; e += 320)
        while (!ld_acq(&flags[e])) __builtin_amdgcn_s_sleep(2);
    }
    __syncthreads();
    {
      int c0 = (steps < CH ? steps : CH) * 75;
      for (int e = tid; e < c0; e += 320)
        ((float4*)gi_buf)[e] = ((const float4*)gic)[e];
    }
    __syncthreads();

    int t0 = 0;
    while (t0 < steps){
      int cnt = steps - t0; if (cnt > CH) cnt = CH;
      for (int s = 0; s < cnt; ++s){
        {
          const f16x8* hp = (const f16x8*)h16;
          f16x8 bf0 = hp[ 0 + gp], bf1 = hp[ 4 + gp], bf2 = hp[ 8 + gp], bf3 = hp[12 + gp];
          #pragma unroll
          for (int m = 0; m < 4; ++m){
            f32x4 acc = {0.f, 0.f, 0.f, 0.f};
            acc = __builtin_amdgcn_mfma_f32_16x16x32_f16(afrag[m][0], bf0, acc, 0, 0, 0);
            acc = __builtin_amdgcn_mfma_f32_16x16x32_f16(afrag[m][1], bf1, acc, 0, 0, 0);
            acc = __builtin_amdgcn_mfma_f32_16x16x32_f16(afrag[m][2], bf2, acc, 0, 0, 0);
            acc = __builtin_amdgcn_mfma_f32_16x16x32_f16(afrag[m][3], bf3, acc, 0, 0, 0);
            int mt = wvid + 5 * m;
            if (rl == 0 && mt < 19)
              *(float4*)&gh_l[mt * 16 + gp * 4] = *(float4*)&acc;
          }
        }
        __syncthreads();
        if (tid < HH){
          const float* gpp = gi_buf + s * 300;
          float r = sigm(gpp[tid]       + gh_l[tid]       + bhr);
          float z = sigm(gpp[tid + 100] + gh_l[tid + 100] + bhz);
          float n = ftanh(gpp[tid + 200] + r * (gh_l[tid + 200] + bhn));
          float o = (1.f - z) * n + z * hreg;
          hreg = o;
          h16[tid] = (_Float16)o;
          hid_buf[s * HH + tid] = o;
        }
        __syncthreads();
      }
      for (int e = tid; e < cnt * 25; e += 320)
        ((float4*)(hid + (size_t)t0 * HH))[e] = ((const float4*)hid_buf)[e];
      int nt0 = t0 + cnt;
      int ncnt = steps - nt0; if (ncnt > CH) ncnt = CH; if (ncnt < 0) ncnt = 0;
      for (int e = tid; e < ncnt; e += 320)
        while (!ld_acq(&flags[nt0 + e])) __builtin_amdgcn_s_sleep(2);
      __syncthreads();                    // drains hid stores + orders spins
      if (tid == 0){ __threadfence(); st_rel(&flags[2048], nt0); }
      for (int e = tid; e < ncnt * 75; e += 320)
        ((float4*)gi_buf)[e] = ((const float4*)(gic + (size_t)nt0 * 300))[e];
      __syncthreads();
      t0 = nt0;
    }
  }

  // ================= PHASE C: batched attention + cls =================
  __syncthreads();
  const int grp = (b == 0) ? 255 : (b - 1);
  const int qbase = grp * 8;
  if (tid < 8){
    int qq = qbase + tid;
    if (qq < TT - 1)
      while (!ld_acq(&flags[qq + 1])) __builtin_amdgcn_s_sleep(8);
  }
  if (tid == 1){
    int need = qbase + 8; if (need > TT - 1) need = TT - 1;
    while (ld_acq(&flags[2048]) < need) __builtin_amdgcn_s_sleep(32);
  }
  if (b == 0 && tid == 0){
    while (!ld_acq(&flags[0])) __builtin_amdgcn_s_sleep(2);
    float l[NCC];
    #pragma unroll
    for (int c = 0; c < NCC; ++c) l[c] = bcls[c];
    for (int h = 0; h < HH; ++h){
      float x = su[h];
      #pragma unroll
      for (int c = 0; c < NCC; ++c) l[c] += x * Wcls[h * NCC + c];
    }
    float m = l[0];
    #pragma unroll
    for (int c = 1; c < NCC; ++c) m = fmaxf(m, l[c]);
    float ssum = 0.f;
    #pragma unroll
    for (int c = 0; c < NCC; ++c) ssum += __expf(l[c] - m);
    float lse = m + __logf(ssum);
    #pragma unroll
    for (int c = 0; c < NCC; ++c) out[c] = l[c] - lse;
  }
  __syncthreads();

  _Float16* MEMb = (_Float16*)smem;              // [40][8][136]
  _Float16* H16b = (_Float16*)(smem + 87040);    // [2][8][136]
  _Float16* GI2b = (_Float16*)(smem + 91392);    // [8][8][100][4]
  float* QLb     = (float*)(smem + 142592);      // [8][104]
  float* SCb     = (float*)(smem + 145920);      // [8][40]
  #define MEM_(w,j,i)   MEMb[((w)*8+(j))*136 + (i)]
  #define H16_(d,j,i)   H16b[((d)*8+(j))*136 + (i)]
  #define GI2_(s,j,u)   GI2b[(((s)*8+(j))*100 + (u))*4]
  #define QL_(j,i)      QLb[(j)*104 + (i)]
  #define SC_(j,w)      SCb[(j)*40 + (w)]

  const int j = rl & 7;
  const int qi = qbase + j;
  int wminj = 39 - qi; if (wminj < 0) wminj = 0;
  if (qi >= TT - 1) wminj = 40;

  f16x8 aW[7][4];
  float bi_[7][3];
  float bh_[4][3]; int cu[4]; bool cv[4];
  const int cbase = (rl < 8) ? 0 : 4;
  if (wvid < 4){
    #pragma unroll
    for (int t = 0; t < 7; ++t){
      int mt = wvid + 4 * t;
      #pragma unroll
      for (int kt = 0; kt < 4; ++kt)
        aW[t][kt] = *(const f16x8*)(wpkW + (size_t)((mt * 4 + kt) * 64 + lane) * 8);
    }
    #pragma unroll
    for (int t = 0; t < 7; ++t){
      int mt = wvid + 4 * t;
      bool v = (mt < 25);
      int uu = v ? (mt * 4 + gp) : 0;
      bi_[t][0] = v ? bih_m[uu]       : 0.f;
      bi_[t][1] = v ? bih_m[uu + 100] : 0.f;
      bi_[t][2] = v ? bih_m[uu + 200] : 0.f;
    }
    #pragma unroll
    for (int tt = 0; tt < 4; ++tt){
      int t = cbase + tt;
      int mt = wvid + 4 * t;
      bool v = (t < 7) && (mt < 25);
      cv[tt] = v;
      int uu = v ? (mt * 4 + gp) : 0;
      cu[tt] = uu;
      bh_[tt][0] = v ? bhh_m[uu]       : 0.f;
      bh_[tt][1] = v ? bhh_m[uu + 100] : 0.f;
      bh_[tt][2] = v ? bhh_m[uu + 200] : 0.f;
    }
  } else {
    #pragma unroll
    for (int tt = 0; tt < 4; ++tt){ cv[tt] = false; cu[tt] = 0;
      bh_[tt][0] = bh_[tt][1] = bh_[tt][2] = 0.f; }
  }

  for (int e = tid; e < 40 * 8 * 34; e += 320){
    int i4 = e % 34, wj = e / 34, w = wj >> 3, jj = wj & 7;
    int qq = qbase + jj;
    int row = qq - 39 + w;
    f16x4 v4 = {0, 0, 0, 0};
    if (i4 < 25 && qq < TT - 1 && row >= 0){
      float4 f = *(const float4*)&hid[(size_t)row * HH + i4 * 4];
      v4[0] = (_Float16)f.x; v4[1] = (_Float16)f.y; v4[2] = (_Float16)f.z; v4[3] = (_Float16)f.w;
    }
    *(f16x4*)&MEM_(w, jj, i4 * 4) = v4;
  }
  for (int e = tid; e < 8 * 104; e += 320){
    int jj = e / 104, ii = e % 104;
    int qq = qbase + jj;
    QL_(jj, ii) = (ii < 100 && qq < TT - 1) ? su[(size_t)(qq + 1) * HH + ii] : 0.f;
  }
  for (int e = tid; e < 2 * 8 * 136; e += 320) H16b[e] = (_Float16)0;
  __syncthreads();

  for (int hop = 0; hop < 3; ++hop){
    // --- scores ---
    for (int e = tid; e < 320; e += 320){
      int jj = e / 40, w = e % 40;
      int qq = qbase + jj;
      int wm = 39 - qq; if (wm < 0) wm = 0; if (qq >= TT - 1) wm = 40;
      if (w >= wm){
        float acc = 0.f;
        #pragma unroll
        for (int g = 0; g < 13; ++g){
          f16x8 m8 = *(const f16x8*)&MEM_(w, jj, g * 8);
          const float* qp = &QL_(jj, g * 8);
          #pragma unroll
          for (int i = 0; i < 8; ++i) acc += (float)m8[i] * qp[i];
        }
        SC_(jj, w) = acc;
      } else SC_(jj, w) = -1e10f;
    }
    __syncthreads();
    // --- softmax ---
    if (tid < 8){
      float m = -3e38f;
      for (int w = 0; w < 40; ++w) m = fmaxf(m, SC_(tid, w));
      float s = 0.f;
      for (int w = 0; w < 40; ++w){ float e = __expf(SC_(tid, w) - m); SC_(tid, w) = e; s += e; }
      float inv = frcp(s);
      for (int w = 0; w < 40; ++w) SC_(tid, w) *= inv;
    }
    __syncthreads();
    // --- context + query update ---
    for (int e = tid; e < 400; e += 320){
      int jj = e / 50, i2 = e % 50;
      float c0 = 0.f, c1 = 0.f;
      for (int w = 0; w < 40; ++w){
        float a = SC_(jj, w);
        f16x2 m2 = *(const f16x2*)&MEM_(w, jj, i2 * 2);
        c0 += a * (float)m2.x; c1 += a * (float)m2.y;
      }
      QL_(jj, i2 * 2)     = ftanh(QL_(jj, i2 * 2)     + c0);
      QL_(jj, i2 * 2 + 1) = ftanh(QL_(jj, i2 * 2 + 1) + c1);
    }
    if (hop == 2){
      __syncthreads();
      for (int e = tid; e < 56; e += 320){
        int jj = e / 7, c = e % 7;
        float lg = bcls[c];
        for (int h = 0; h < HH; ++h) lg += QL_(jj, h) * Wcls[h * NCC + c];
        SC_(jj, c) = lg;
      }
      __syncthreads();
      if (tid < 8){
        int qq = qbase + tid;
        if (qq < TT - 1){
          float m = SC_(tid, 0);
          #pragma unroll
          for (int c = 1; c < NCC; ++c) m = fmaxf(m, SC_(tid, c));
          float ssum = 0.f;
          #pragma unroll
          for (int c = 0; c < NCC; ++c) ssum += __expf(SC_(tid, c) - m);
          float lse = m + __logf(ssum);
          #pragma unroll
          for (int c = 0; c < NCC; ++c) out[(size_t)(qq + 1) * NCC + c] = SC_(tid, c) - lse;
        }
      }
      break;
    }
    for (int e = tid; e < 800; e += 320) H16_(0, e / 100, e % 100) = (_Float16)0;
    float hrg[4] = {0.f, 0.f, 0.f, 0.f};
    __syncthreads();

    for (int c = 0; c < 5; ++c){
      // GI2 = WihPack @ MEM[8c..8c+7] + bih
      if (wvid < 4){
        #pragma unroll
        for (int nt = 0; nt < 4; ++nt){
          f16x8 bf[4];
          #pragma unroll
          for (int kt = 0; kt < 4; ++kt)
            bf[kt] = *(const f16x8*)&MEM_(c * 8 + nt * 2 + (rl >> 3), rl & 7, kt * 32 + gp * 8);
          #pragma unroll
          for (int t = 0; t < 7; ++t){
            int mt = wvid + 4 * t;
            if (mt < 25){
              f32x4 ac = {0.f, 0.f, 0.f, 0.f};
              #pragma unroll
              for (int kt = 0; kt < 4; ++kt){
                f16x8 ai = *(const f16x8*)(wpkI + (size_t)((mt * 4 + kt) * 64 + lane) * 8);
                ac = __builtin_amdgcn_mfma_f32_16x16x32_f16(ai, bf[kt], ac, 0, 0, 0);
              }
              int uu = mt * 4 + gp;
              int s8 = nt * 2 + (rl >> 3), jj = rl & 7;
              f16x4 g4;
              g4[0] = (_Float16)(ac[0] + bi_[t][0]);
              g4[1] = (_Float16)(ac[1] + bi_[t][1]);
              g4[2] = (_Float16)(ac[2] + bi_[t][2]);
              g4[3] = (_Float16)0.f;
              *(f16x4*)&GI2_(s8, jj, uu) = g4;
            }
          }
        }
      }
      __syncthreads();
      for (int s = 0; s < 8; ++s){
        int w = c * 8 + s;
        if (wvid < 4){
          f16x8 b0 = *(const f16x8*)&H16_(w & 1, j,       gp * 8);
          f16x8 b1 = *(const f16x8*)&H16_(w & 1, j, 32  + gp * 8);
          f16x8 b2 = *(const f16x8*)&H16_(w & 1, j, 64  + gp * 8);
          f16x8 b3 = *(const f16x8*)&H16_(w & 1, j, 96  + gp * 8);
          f32x4 acc[7];
          #pragma unroll
          for (int t = 0; t < 7; ++t){
            int mt = wvid + 4 * t;
            f32x4 a = {0.f, 0.f, 0.f, 0.f};
            if (mt < 25){
              a = __builtin_amdgcn_mfma_f32_16x16x32_f16(aW[t][0], b0, a, 0, 0, 0);
              a = __builtin_amdgcn_mfma_f32_16x16x32_f16(aW[t][1], b1, a, 0, 0, 0);
              a = __builtin_amdgcn_mfma_f32_16x16x32_f16(aW[t][2], b2, a, 0, 0, 0);
              a = __builtin_amdgcn_mfma_f32_16x16x32_f16(aW[t][3], b3, a, 0, 0, 0);
            }
            acc[t] = a;
          }
          const bool vw = (w >= wminj);
          #pragma unroll
          for (int tt = 0; tt < 4; ++tt){
            if (cv[tt]){
              f32x4 ac = (rl < 8) ? acc[tt] : acc[(tt + 4 < 7) ? (tt + 4) : 6];
              f16x4 g4 = *(const f16x4*)&GI2_(s, j, cu[tt]);
              float r = sigm((float)g4[0] + ac[0] + bh_[tt][0]);
              float z = sigm((float)g4[1] + ac[1] + bh_[tt][1]);
              float n = ftanh((float)g4[2] + r * (ac[2] + bh_[tt][2]));
              float o = vw ? ((1.f - z) * n + z * hrg[tt]) : hrg[tt];
              hrg[tt] = o;
              H16_((w + 1) & 1, j, cu[tt]) = (_Float16)o;
              MEM_(w, j, cu[tt]) = (_Float16)o;
            }
          }
        }
        __syncthreads();
      }
    }
  }
  #undef MEM_
  #undef H16_
  #undef GI2_
  #undef QL_
  #undef SC_
}

extern "C" void kernel_launch(void* const* d_in, const int* in_sizes, int n_in,
                              void* d_out, int out_size, void* d_ws, size_t ws_size,
                              hipStream_t stream)
{
  const int* sents  = (const int*)d_in[0];
  // d_in[1] = lengths (unused by the reference)
  const float* emb    = (const float*)d_in[2];
  const float* Wc3    = (const float*)d_in[3];  const float* bc3 = (const float*)d_in[4];
  const float* Wc4    = (const float*)d_in[5];  const float* bc4 = (const float*)d_in[6];
  const float* Wc5    = (const float*)d_in[7];  const float* bc5 = (const float*)d_in[8];
  const float* Wt     = (const float*)d_in[9];  const float* bt  = (const float*)d_in[10];
  const float* Wih_c  = (const float*)d_in[11]; const float* Whh_c = (const float*)d_in[12];
  const float* bih_c  = (const float*)d_in[13]; const float* bhh_c = (const float*)d_in[14];
  const float* Wih_m  = (const float*)d_in[15]; const float* Whh_m = (const float*)d_in[16];
  const float* bih_m  = (const float*)d_in[17]; const float* bhh_m = (const float*)d_in[18];
  const float* Wcls   = (const float*)d_in[19]; const float* bcls  = (const float*)d_in[20];

  float* ws    = (float*)d_ws;
  float* su    = ws;                             // 2048*100
  float* gic   = su  + 204800;                   // 2047*300
  float* hid   = gic + 614100;                   // 2047*100
  _Float16* wtp  = (_Float16*)(hid + 204700);    // 245760 f16 packed conv weights
  _Float16* wpkW = wtp + 245760;                 // 57344 f16 packed Whh_m frags
  _Float16* wpkI = wpkW + 57344;                 // 57344 f16 packed Wih_m frags
  int* flags     = (int*)(wpkI + 57344);         // 2049 flags (2048 = hid watermark)

  k_prep <<<480, 256, 0, stream>>>(Wc3, Wc4, Wc5, wtp);
  k_prep2<<<2,   256, 0, stream>>>(Whh_m, Wih_m, wpkW, wpkI);
  k_zero <<<9,   256, 0, stream>>>(flags);
  k_mega <<<256, 320, 0, stream>>>(sents, emb, wtp, bc3, bc4, bc5, Wt, bt,
                                   Wih_c, bih_c, Whh_c, bhh_c,
                                   wpkW, wpkI, bih_m, bhh_m, Wcls, bcls,
                                   su, gic, hid, flags, (float*)d_out);
}

// Round 11
// 1702.600 us; speedup vs baseline: 1.1232x; 1.1232x over previous
//
#include <hip/hip_runtime.h>

#define TT 2048
#define LL 50
#define DD 300
#define HH 100
#define NCC 7

typedef unsigned short u16;
typedef unsigned int u32;
typedef _Float16 f16x2 __attribute__((ext_vector_type(2)));
typedef _Float16 f16x4 __attribute__((ext_vector_type(4)));
typedef _Float16 f16x8 __attribute__((ext_vector_type(8)));
typedef float f32x4 __attribute__((ext_vector_type(4)));

__device__ __forceinline__ float frcp(float x){ return __builtin_amdgcn_rcpf(x); }
__device__ __forceinline__ float sigm(float x){ return frcp(1.f + __expf(-x)); }
__device__ __forceinline__ float ftanh(float x){ return 1.f - 2.f * frcp(1.f + __expf(2.f * x)); }

#if defined(__has_builtin)
#if __has_builtin(__builtin_amdgcn_fdot2)
#define HAS_FDOT2 1
#endif
#endif
__device__ __forceinline__ float fdot2(f16x2 a, f16x2 b, float c){
#ifdef HAS_FDOT2
  return __builtin_amdgcn_fdot2(a, b, c, false);
#else
  return c + (float)a.x * (float)b.x + (float)a.y * (float)b.y;
#endif
}
__device__ __forceinline__ f16x2 pk(float x, float y){ f16x2 r; r.x = (_Float16)x; r.y = (_Float16)y; return r; }

// ---------------- Kernel 0: pack conv weights into MFMA B-fragment order ----------------
__global__ __launch_bounds__(256) void k_prep(const float* __restrict__ Wc3,
    const float* __restrict__ Wc4, const float* __restrict__ Wc5, _Float16* __restrict__ wtp)
{
  const int t = blockIdx.x;
  int kki, ntile, kt;
  if (t < 120){ kki = 0; ntile = t / 30;        kt = t % 30; }
  else if (t < 280){ kki = 1; int r = t - 120; ntile = r / 40; kt = r % 40; }
  else { kki = 2; int r = t - 280;             ntile = r / 50; kt = r % 50; }
  const float* W = (kki == 0) ? Wc3 : ((kki == 1) ? Wc4 : Wc5);
  const int kk = 3 + kki;
  #pragma unroll
  for (int u = 0; u < 2; ++u){
    int e = threadIdx.x * 2 + u;       // 0..511
    int lane = e >> 3, i = e & 7;
    int k = kt * 32 + (lane >> 4) * 8 + i;
    int f = ntile * 16 + (lane & 15);
    int j = k / 320, d = k - j * 320;
    float v = (d < DD) ? W[((size_t)f * kk + j) * DD + d] : 0.f;
    wtp[(size_t)t * 512 + e] = (_Float16)v;
  }
}

// ---------------- Kernel 0b: pack Whh_m / Wih_m into packed-row (unit*4+gate) A-fragments ----
__global__ __launch_bounds__(256) void k_prep2(const float* __restrict__ Whh,
    const float* __restrict__ Wih, _Float16* __restrict__ wpkW, _Float16* __restrict__ wpkI)
{
  const float* W = (blockIdx.x == 0) ? Whh : Wih;
  _Float16* dst  = (blockIdx.x == 0) ? wpkW : wpkI;
  for (int idx = threadIdx.x; idx < 28 * 4 * 64 * 8; idx += 256){
    int i = idx & 7, lane = (idx >> 3) & 63, kt = (idx >> 9) & 3, mt = idx >> 11;
    int rl = lane & 15, gp = lane >> 4;
    int p = mt * 16 + rl;
    int k = kt * 32 + gp * 8 + i;
    int uu = p >> 2, g = p & 3;
    float v = (mt < 25 && g < 3 && k < 100) ? W[(size_t)(uu + 100 * g) * 100 + k] : 0.f;
    dst[idx] = (_Float16)v;
  }
}

// ---------------- Kernel 1: embedding + TextCNN(3,4,5) via MFMA + max-relu + s_utt ----------------
#define WST 328
__global__ __launch_bounds__(256) void k_cnn(const int* __restrict__ sents,
    const float* __restrict__ emb, const _Float16* __restrict__ wtp,
    const float* __restrict__ bc3, const float* __restrict__ bc4, const float* __restrict__ bc5,
    const float* __restrict__ Wt,  const float* __restrict__ bt,
    float* __restrict__ su)
{
  __shared__ __attribute__((aligned(16))) _Float16 w16[52 * WST];
  __shared__ float feats[192];
  __shared__ int ids[LL];
  const int tid = threadIdx.x;
  const int s = blockIdx.x;

  if (tid < LL) ids[tid] = sents[s * LL + tid];
  for (int e = tid; e < 52 * WST / 2; e += 256) ((u32*)w16)[e] = 0u;
  __syncthreads();
  for (int e = tid; e < LL * 75; e += 256){
    int l = e / 75, d4 = (e - l * 75) * 4;
    float4 v = *(const float4*)&emb[(size_t)ids[l] * DD + d4];
    _Float16* p = &w16[l * WST + d4];
    p[0] = (_Float16)v.x; p[1] = (_Float16)v.y; p[2] = (_Float16)v.z; p[3] = (_Float16)v.w;
  }
  __syncthreads();

  const int lane = tid & 63, wid = tid >> 6;
  const int rl = lane & 15, gp = lane >> 4;
  const int kkstart[3] = {0, 120, 280};
  float fmaxv[3];
  #pragma unroll
  for (int kki = 0; kki < 3; ++kki){
    const int kk = 3 + kki, nkt = kk * 10, Pk = LL - kk + 1;
    f32x4 acc0 = {0.f,0.f,0.f,0.f}, acc1 = acc0, acc2 = acc0;
    const f16x8* bp = (const f16x8*)(wtp + (size_t)(kkstart[kki] + wid * nkt) * 512) + lane;
    int j = 0, d = gp * 8;
    for (int kt = 0; kt < nkt; ++kt){
      f16x8 b  = bp[(size_t)kt * 64];
      f16x8 a0 = *(const f16x8*)&w16[(rl      + j) * WST + d];
      f16x8 a1 = *(const f16x8*)&w16[(16 + rl + j) * WST + d];
      f16x8 a2 = *(const f16x8*)&w16[(32 + rl + j) * WST + d];
      acc0 = __builtin_amdgcn_mfma_f32_16x16x32_f16(a0, b, acc0, 0, 0, 0);
      acc1 = __builtin_amdgcn_mfma_f32_16x16x32_f16(a1, b, acc1, 0, 0, 0);
      acc2 = __builtin_amdgcn_mfma_f32_16x16x32_f16(a2, b, acc2, 0, 0, 0);
      d += 32; if (d >= 320){ d -= 320; ++j; }
    }
    float m = -1e30f;
    #pragma unroll
    for (int r = 0; r < 4; ++r){
      int p0 = gp * 4 + r;
      if (p0 < Pk)      m = fmaxf(m, acc0[r]);
      if (16 + p0 < Pk) m = fmaxf(m, acc1[r]);
      if (32 + p0 < Pk) m = fmaxf(m, acc2[r]);
    }
    m = fmaxf(m, __shfl_xor(m, 16));
    m = fmaxf(m, __shfl_xor(m, 32));
    fmaxv[kki] = m;
  }
  if (lane < 16){
    feats[  0 + wid * 16 + lane] = fmaxv[0];
    feats[ 64 + wid * 16 + lane] = fmaxv[1];
    feats[128 + wid * 16 + lane] = fmaxv[2];
  }
  __syncthreads();
  if (tid < 192){
    float bias = (tid < 64) ? bc3[tid] : ((tid < 128) ? bc4[tid - 64] : bc5[tid - 128]);
    feats[tid] = fmaxf(0.f, feats[tid] + bias);
  }
  __syncthreads();
  if (tid < HH){
    float acc = bt[tid];
    for (int c = 0; c < 192; ++c)
      acc += feats[c] * Wt[c * HH + tid];
    su[(size_t)s * HH + tid] = ftanh(acc);
  }
}

// ---------------- Kernel 2/4: gi = src @ W^T + b as an MFMA GEMM ----------------
// src [R][100] f32, W [300][100] f32 (row-major, k contiguous -> B-frags load
// directly, no packing). A-frag: row=lane&15, k=(lane>>4)*8+i (k_cnn-proven).
// D: col=lane&15 (n), row=(lane>>4)*4+reg (m). Grid (32, 2): 64-row m-blocks
// (4 waves x 1 m-tile), n split 10/9 tiles. Bias added in epilogue.
__global__ __launch_bounds__(256) void k_ggi(const float* __restrict__ src, int R,
    const float* __restrict__ W, const float* __restrict__ b, float* __restrict__ dst)
{
  const int tid = threadIdx.x;
  const int lane = tid & 63, wv = tid >> 6;
  const int rl = lane & 15, gp = lane >> 4;
  const int m0 = blockIdx.x * 64 + wv * 16;
  const int nt0 = blockIdx.y * 10;
  const int ntn = (blockIdx.y == 0) ? 10 : 9;

  // A-frags for this wave's 16 rows (f32 -> f16 in-register)
  f16x8 af[4];
  {
    int mrow = m0 + rl; if (mrow >= R) mrow = 0;   // clamp; garbage rows never stored
    const float* sr = src + (size_t)mrow * 100;
    #pragma unroll
    for (int kt = 0; kt < 4; ++kt){
      f16x8 f = {0,0,0,0,0,0,0,0};
      int k0 = kt * 32 + gp * 8;
      if (k0 < 100){
        float4 x = *(const float4*)(sr + k0);
        f[0]=(_Float16)x.x; f[1]=(_Float16)x.y; f[2]=(_Float16)x.z; f[3]=(_Float16)x.w;
        if (k0 + 4 < 100){
          float4 y = *(const float4*)(sr + k0 + 4);
          f[4]=(_Float16)y.x; f[5]=(_Float16)y.y; f[6]=(_Float16)y.z; f[7]=(_Float16)y.w;
        }
      }
      af[kt] = f;
    }
  }

  for (int nt = nt0; nt < nt0 + ntn; ++nt){
    int n = nt * 16 + rl;
    const float* wr = W + (size_t)(n < 300 ? n : 0) * 100;
    f32x4 acc = {0.f,0.f,0.f,0.f};
    #pragma unroll
    for (int kt = 0; kt < 4; ++kt){
      f16x8 bf = {0,0,0,0,0,0,0,0};
      int k0 = kt * 32 + gp * 8;
      if (k0 < 100){
        float4 x = *(const float4*)(wr + k0);
        bf[0]=(_Float16)x.x; bf[1]=(_Float16)x.y; bf[2]=(_Float16)x.z; bf[3]=(_Float16)x.w;
        if (k0 + 4 < 100){
          float4 y = *(const float4*)(wr + k0 + 4);
          bf[4]=(_Float16)y.x; bf[5]=(_Float16)y.y; bf[6]=(_Float16)y.z; bf[7]=(_Float16)y.w;
        }
      }
      acc = __builtin_amdgcn_mfma_f32_16x16x32_f16(af[kt], bf, acc, 0, 0, 0);
    }
    if (n < 300){
      float bias = b[n];
      #pragma unroll
      for (int r = 0; r < 4; ++r){
        int m = m0 + gp * 4 + r;
        if (m < R) dst[(size_t)m * 300 + n] = acc[r] + bias;
      }
    }
  }
}

// ---------------- Kernel 3: sequential context-GRU scan (r5 version, best measured) ----------------
#define CH 32
__global__ __launch_bounds__(320, 1) void k_scan(const float* __restrict__ gi,
    const float* __restrict__ Whh, const float* __restrict__ bhh,
    float* __restrict__ hid, int steps)
{
  __shared__ __attribute__((aligned(16))) _Float16 h16[128];
  __shared__ __attribute__((aligned(16))) float gh_l[304];
  __shared__ float gi_buf[CH * 300];
  __shared__ float hid_buf[CH * HH];
  const int tid = threadIdx.x;
  const int lane = tid & 63, wvid = tid >> 6;   // 5 waves
  const int rl = lane & 15, gp = lane >> 4;

  f16x8 afrag[4][4];
  #pragma unroll
  for (int m = 0; m < 4; ++m){
    int mt = wvid + 5 * m;
    int row = mt * 16 + rl;
    #pragma unroll
    for (int kt = 0; kt < 4; ++kt){
      f16x8 f;
      #pragma unroll
      for (int i = 0; i < 8; ++i){
        int k = kt * 32 + gp * 8 + i;
        float v = (row < 300 && k < 100) ? Whh[(size_t)row * 100 + k] : 0.f;
        f[i] = (_Float16)v;
      }
      afrag[m][kt] = f;
    }
  }
  float bhr = 0.f, bhz = 0.f, bhn = 0.f, hreg = 0.f;
  if (tid < HH){ bhr = bhh[tid]; bhz = bhh[tid + 100]; bhn = bhh[tid + 200]; }
  if (tid < 128) h16[tid] = (_Float16)0.f;
  {
    int c0 = (steps < CH ? steps : CH) * 75;
    for (int e = tid; e < c0; e += 320)
      ((float4*)gi_buf)[e] = ((const float4*)gi)[e];
  }
  __syncthreads();

  int t0 = 0;
  while (t0 < steps){
    int cnt = steps - t0; if (cnt > CH) cnt = CH;
    for (int s = 0; s < cnt; ++s){
      {
        const f16x8* hp = (const f16x8*)h16;
        f16x8 bf0 = hp[ 0 + gp], bf1 = hp[ 4 + gp], bf2 = hp[ 8 + gp], bf3 = hp[12 + gp];
        #pragma unroll
        for (int m = 0; m < 4; ++m){
          f32x4 acc = {0.f, 0.f, 0.f, 0.f};
          acc = __builtin_amdgcn_mfma_f32_16x16x32_f16(afrag[m][0], bf0, acc, 0, 0, 0);
          acc = __builtin_amdgcn_mfma_f32_16x16x32_f16(afrag[m][1], bf1, acc, 0, 0, 0);
          acc = __builtin_amdgcn_mfma_f32_16x16x32_f16(afrag[m][2], bf2, acc, 0, 0, 0);
          acc = __builtin_amdgcn_mfma_f32_16x16x32_f16(afrag[m][3], bf3, acc, 0, 0, 0);
          int mt = wvid + 5 * m;
          if (rl == 0 && mt < 19)
            *(float4*)&gh_l[mt * 16 + gp * 4] = *(float4*)&acc;
        }
      }
      __syncthreads();
      if (tid < HH){
        const float* gpp = gi_buf + s * 300;
        float r = sigm(gpp[tid]       + gh_l[tid]       + bhr);
        float z = sigm(gpp[tid + 100] + gh_l[tid + 100] + bhz);
        float n = ftanh(gpp[tid + 200] + r * (gh_l[tid + 200] + bhn));
        float o = (1.f - z) * n + z * hreg;
        hreg = o;
        h16[tid] = (_Float16)o;
        hid_buf[s * HH + tid] = o;
      }
      __syncthreads();
    }
    for (int e = tid; e < cnt * 25; e += 320)
      ((float4*)(hid + (size_t)t0 * HH))[e] = ((const float4*)hid_buf)[e];
    int nt0 = t0 + cnt;
    int ncnt = steps - nt0; if (ncnt > CH) ncnt = CH; if (ncnt < 0) ncnt = 0;
    for (int e = tid; e < ncnt * 75; e += 320)
      ((float4*)gi_buf)[e] = ((const float4*)(gi + (size_t)nt0 * 300))[e];
    __syncthreads();
    t0 = nt0;
  }
}

// ---------------- Kernel 5: BATCHED 3-hop windowed memory attention ----------------
__global__ __launch_bounds__(256, 1) void k_att2(
    const float* __restrict__ su, const float* __restrict__ hid, const float* __restrict__ gm,
    const _Float16* __restrict__ wpkW, const _Float16* __restrict__ wpkI,
    const float* __restrict__ bih, const float* __restrict__ bhh,
    float* __restrict__ scont)
{
  __shared__ __attribute__((aligned(16))) _Float16 MEM[40][8][136];
  __shared__ __attribute__((aligned(16))) _Float16 H16[2][8][136];
  __shared__ __attribute__((aligned(16))) _Float16 GI2[8][8][100][4];
  __shared__ float QL[8][104];
  __shared__ float SC[8][40];

  const int tid = threadIdx.x;
  const int lane = tid & 63, wvid = tid >> 6;   // 4 waves
  const int rl = lane & 15, gp = lane >> 4;
  const int qbase = blockIdx.x * 8;
  const int j = rl & 7;
  const int qi = qbase + j;
  int wminj = 39 - qi; if (wminj < 0) wminj = 0;
  if (qi >= TT - 1) wminj = 40;                 // invalid query -> never valid

  f16x8 aW[7][4];
  #pragma unroll
  for (int t = 0; t < 7; ++t){
    int mt = wvid + 4 * t;
    #pragma unroll
    for (int kt = 0; kt < 4; ++kt)
      aW[t][kt] = *(const f16x8*)(wpkW + (size_t)((mt * 4 + kt) * 64 + lane) * 8);
  }
  float bi_[7][3];
  #pragma unroll
  for (int t = 0; t < 7; ++t){
    int mt = wvid + 4 * t;
    bool v = (mt < 25);
    int uu = v ? (mt * 4 + gp) : 0;
    bi_[t][0] = v ? bih[uu]       : 0.f;
    bi_[t][1] = v ? bih[uu + 100] : 0.f;
    bi_[t][2] = v ? bih[uu + 200] : 0.f;
  }
  const int cbase = (rl < 8) ? 0 : 4;
  float bh_[4][3]; int cu[4]; bool cv[4];
  #pragma unroll
  for (int tt = 0; tt < 4; ++tt){
    int t = cbase + tt;
    int mt = wvid + 4 * t;
    bool v = (t < 7) && (mt < 25);
    cv[tt] = v;
    int uu = v ? (mt * 4 + gp) : 0;
    cu[tt] = uu;
    bh_[tt][0] = v ? bhh[uu]       : 0.f;
    bh_[tt][1] = v ? bhh[uu + 100] : 0.f;
    bh_[tt][2] = v ? bhh[uu + 200] : 0.f;
  }

  for (int e = tid; e < 40 * 8 * 34; e += 256){
    int i4 = e % 34, wj = e / 34, w = wj >> 3, jj = wj & 7;
    int qq = qbase + jj;
    int row = qq - 39 + w;
    f16x4 v4 = {0, 0, 0, 0};
    if (i4 < 25 && qq < TT - 1 && row >= 0){
      float4 f = *(const float4*)&hid[(size_t)row * HH + i4 * 4];
      v4[0] = (_Float16)f.x; v4[1] = (_Float16)f.y; v4[2] = (_Float16)f.z; v4[3] = (_Float16)f.w;
    }
    *(f16x4*)&MEM[w][jj][i4 * 4] = v4;
  }
  for (int e = tid; e < 8 * 104; e += 256){
    int jj = e / 104, ii = e % 104;
    int qq = qbase + jj;
    QL[jj][ii] = (ii < 100 && qq < TT - 1) ? su[(size_t)(qq + 1) * HH + ii] : 0.f;
  }
  for (int e = tid; e < 2 * 8 * 136; e += 256) ((_Float16*)H16)[e] = (_Float16)0;
  __syncthreads();

  for (int hop = 0; hop < 3; ++hop){
    for (int e = tid; e < 320; e += 256){
      int jj = e / 40, w = e % 40;
      int qq = qbase + jj;
      int wm = 39 - qq; if (wm < 0) wm = 0; if (qq >= TT - 1) wm = 40;
      float acc = 0.f;
      if (w >= wm){
        #pragma unroll
        for (int g = 0; g < 13; ++g){
          f16x8 m8 = *(const f16x8*)&MEM[w][jj][g * 8];
          const float* qp = &QL[jj][g * 8];
          #pragma unroll
          for (int i = 0; i < 8; ++i) acc += (float)m8[i] * qp[i];
        }
        SC[jj][w] = acc;
      } else SC[jj][w] = -1e10f;
    }
    __syncthreads();
    if (tid < 8){
      float m = -3e38f;
      for (int w = 0; w < 40; ++w) m = fmaxf(m, SC[tid][w]);
      float s = 0.f;
      for (int w = 0; w < 40; ++w){ float e = __expf(SC[tid][w] - m); SC[tid][w] = e; s += e; }
      float inv = frcp(s);
      for (int w = 0; w < 40; ++w) SC[tid][w] *= inv;
    }
    __syncthreads();
    for (int e = tid; e < 400; e += 256){
      int jj = e / 50, i2 = e % 50;
      float c0 = 0.f, c1 = 0.f;
      for (int w = 0; w < 40; ++w){
        float a = SC[jj][w];
        f16x2 m2 = *(const f16x2*)&MEM[w][jj][i2 * 2];
        c0 += a * (float)m2.x; c1 += a * (float)m2.y;
      }
      float q0 = ftanh(QL[jj][i2 * 2]     + c0);
      float q1 = ftanh(QL[jj][i2 * 2 + 1] + c1);
      QL[jj][i2 * 2] = q0; QL[jj][i2 * 2 + 1] = q1;
      if (hop == 2){
        int qq = qbase + jj;
        if (qq < TT - 1)
          *(float2*)&scont[(size_t)(qq + 1) * HH + i2 * 2] = make_float2(q0, q1);
      }
    }
    if (hop == 2) break;
    for (int e = tid; e < 800; e += 256) H16[0][e / 100][e % 100] = (_Float16)0;
    float hrg[4] = {0.f, 0.f, 0.f, 0.f};
    __syncthreads();

    for (int c = 0; c < 5; ++c){
      if (hop == 0){
        for (int e = tid; e < 6400; e += 256){
          int s8 = e / 800, jj = (e / 100) & 7, uu = e % 100;
          int qq = qbase + jj;
          int row = qq - 39 + c * 8 + s8;
          f16x4 g4 = {0, 0, 0, 0};
          if (qq < TT - 1 && row >= 0){
            const float* gr = &gm[(size_t)row * 300];
            g4[0] = (_Float16)gr[uu]; g4[1] = (_Float16)gr[uu + 100]; g4[2] = (_Float16)gr[uu + 200];
          }
          *(f16x4*)&GI2[s8][jj][uu][0] = g4;
        }
      } else {
        #pragma unroll
        for (int nt = 0; nt < 4; ++nt){
          f16x8 bf[4];
          #pragma unroll
          for (int kt = 0; kt < 4; ++kt)
            bf[kt] = *(const f16x8*)&MEM[c * 8 + nt * 2 + (rl >> 3)][rl & 7][kt * 32 + gp * 8];
          #pragma unroll
          for (int t = 0; t < 7; ++t){
            int mt = wvid + 4 * t;
            if (mt < 25){
              f32x4 ac = {0.f, 0.f, 0.f, 0.f};
              #pragma unroll
              for (int kt = 0; kt < 4; ++kt){
                f16x8 ai = *(const f16x8*)(wpkI + (size_t)((mt * 4 + kt) * 64 + lane) * 8);
                ac = __builtin_amdgcn_mfma_f32_16x16x32_f16(ai, bf[kt], ac, 0, 0, 0);
              }
              int uu = mt * 4 + gp;
              int s8 = nt * 2 + (rl >> 3), jj = rl & 7;
              f16x4 g4;
              g4[0] = (_Float16)(ac[0] + bi_[t][0]);
              g4[1] = (_Float16)(ac[1] + bi_[t][1]);
              g4[2] = (_Float16)(ac[2] + bi_[t][2]);
              g4[3] = (_Float16)0.f;
              *(f16x4*)&GI2[s8][jj][uu][0] = g4;
            }
          }
        }
      }
      __syncthreads();
      for (int s = 0; s < 8; ++s){
        int w = c * 8 + s;
        const _Float16 (*hs)[136] = H16[w & 1];
        _Float16 (*hd)[136] = H16[(w + 1) & 1];
        f16x8 b0 = *(const f16x8*)&hs[j][      gp * 8];
        f16x8 b1 = *(const f16x8*)&hs[j][32  + gp * 8];
        f16x8 b2 = *(const f16x8*)&hs[j][64  + gp * 8];
        f16x8 b3 = *(const f16x8*)&hs[j][96  + gp * 8];
        f32x4 acc[7];
        #pragma unroll
        for (int t = 0; t < 7; ++t){
          int mt = wvid + 4 * t;
          f32x4 a = {0.f, 0.f, 0.f, 0.f};
          if (mt < 25){
            a = __builtin_amdgcn_mfma_f32_16x16x32_f16(aW[t][0], b0, a, 0, 0, 0);
            a = __builtin_amdgcn_mfma_f32_16x16x32_f16(aW[t][1], b1, a, 0, 0, 0);
            a = __builtin_amdgcn_mfma_f32_16x16x32_f16(aW[t][2], b2, a, 0, 0, 0);
            a = __builtin_amdgcn_mfma_f32_16x16x32_f16(aW[t][3], b3, a, 0, 0, 0);
          }
          acc[t] = a;
        }
        const bool vw = (w >= wminj);
        #pragma unroll
        for (int tt = 0; tt < 4; ++tt){
          if (cv[tt]){
            f32x4 ac = (rl < 8) ? acc[tt] : acc[(tt + 4 < 7) ? (tt + 4) : 6];
            f16x4 g4 = *(const f16x4*)&GI2[s][j][cu[tt]][0];
            float r = sigm((float)g4[0] + ac[0] + bh_[tt][0]);
            float z = sigm((float)g4[1] + ac[1] + bh_[tt][1]);
            float n = ftanh((float)g4[2] + r * (ac[2] + bh_[tt][2]));
            float o = vw ? ((1.f - z) * n + z * hrg[tt]) : hrg[tt];
            hrg[tt] = o;
            hd[j][cu[tt]]     = (_Float16)o;
            MEM[w][j][cu[tt]] = (_Float16)o;
          }
        }
        __syncthreads();
      }
    }
  }
}

// ---------------- Kernel 6: classifier + log_softmax ----------------
__global__ __launch_bounds__(256) void k_cls(const float* __restrict__ su, const float* __restrict__ scont,
    const float* __restrict__ Wcls, const float* __restrict__ bcls, float* __restrict__ out)
{
  __shared__ float wl[HH * NCC];
  __shared__ float bl[NCC];
  const int tid = threadIdx.x;
  for (int e = tid; e < HH * NCC; e += 256) wl[e] = Wcls[e];
  if (tid < NCC) bl[tid] = bcls[tid];
  __syncthreads();
  int r = blockIdx.x * 256 + tid;
  if (r < TT){
    const float* v = (r == 0) ? su : (scont + (size_t)r * HH);
    float l[NCC];
    #pragma unroll
    for (int c = 0; c < NCC; ++c) l[c] = bl[c];
    for (int h = 0; h < HH; ++h){
      float x = v[h];
      #pragma unroll
      for (int c = 0; c < NCC; ++c) l[c] += x * wl[h * NCC + c];
    }
    float m = l[0];
    #pragma unroll
    for (int c = 1; c < NCC; ++c) m = fmaxf(m, l[c]);
    float ssum = 0.f;
    #pragma unroll
    for (int c = 0; c < NCC; ++c) ssum += __expf(l[c] - m);
    float lse = m + __logf(ssum);
    #pragma unroll
    for (int c = 0; c < NCC; ++c) out[(size_t)r * NCC + c] = l[c] - lse;
  }
}

extern "C" void kernel_launch(void* const* d_in, const int* in_sizes, int n_in,
                              void* d_out, int out_size, void* d_ws, size_t ws_size,
                              hipStream_t stream)
{
  const int* sents  = (const int*)d_in[0];
  // d_in[1] = lengths (unused by the reference)
  const float* emb    = (const float*)d_in[2];
  const float* Wc3    = (const float*)d_in[3];  const float* bc3 = (const float*)d_in[4];
  const float* Wc4    = (const float*)d_in[5];  const float* bc4 = (const float*)d_in[6];
  const float* Wc5    = (const float*)d_in[7];  const float* bc5 = (const float*)d_in[8];
  const float* Wt     = (const float*)d_in[9];  const float* bt  = (const float*)d_in[10];
  const float* Wih_c  = (const float*)d_in[11]; const float* Whh_c = (const float*)d_in[12];
  const float* bih_c  = (const float*)d_in[13]; const float* bhh_c = (const float*)d_in[14];
  const float* Wih_m  = (const float*)d_in[15]; const float* Whh_m = (const float*)d_in[16];
  const float* bih_m  = (const float*)d_in[17]; const float* bhh_m = (const float*)d_in[18];
  const float* Wcls   = (const float*)d_in[19]; const float* bcls  = (const float*)d_in[20];

  float* ws    = (float*)d_ws;
  float* su    = ws;                  // 2048*100
  float* gic   = su  + 204800;        // 2047*300 (dead after k_scan)
  float* hid   = gic + 614100;        // 2047*100
  float* gm    = gic;                 // aliases gic (gic consumed before gm written)
  float* scont = hid + 204700;        // 2048*100 (row 0 unused)
  _Float16* wtp  = (_Float16*)(scont + 204800);  // 245760 f16 packed conv weights
  _Float16* wpkW = wtp + 245760;                 // 57344 f16 packed Whh_m frags
  _Float16* wpkI = wpkW + 57344;                 // 57344 f16 packed Wih_m frags

  k_prep <<<480,    256, 0, stream>>>(Wc3, Wc4, Wc5, wtp);
  k_prep2<<<2,      256, 0, stream>>>(Whh_m, Wih_m, wpkW, wpkI);
  k_cnn  <<<TT,     256, 0, stream>>>(sents, emb, wtp, bc3, bc4, bc5, Wt, bt, su);
  k_ggi  <<<dim3(32, 2), 256, 0, stream>>>(su, TT - 1, Wih_c, bih_c, gic);
  k_scan <<<1,      320, 0, stream>>>(gic, Whh_c, bhh_c, hid, TT - 1);
  k_ggi  <<<dim3(32, 2), 256, 0, stream>>>(hid, TT - 1, Wih_m, bih_m, gm);
  k_att2 <<<256,    256, 0, stream>>>(su, hid, gm, wpkW, wpkI, bih_m, bhh_m, scont);
  k_cls  <<<(TT + 255) / 256, 256, 0, stream>>>(su, scont, Wcls, bcls, (float*)d_out);
}